// Round 1
// baseline (725.765 us; speedup 1.0000x reference)
//
#include <hip/hip_runtime.h>
#include <hip/hip_bf16.h>
#include <cstdint>
#include <cstddef>

// ---------------- model constants ----------------
#define TH 0.007f

// ---------------- workspace layout (float offsets) ----------------
#define OFF_S1RAW   0u          // 128*100*64
#define OFF_S2RAW   819200u
#define OFF_IALL    1638400u    // 128*100*64
#define OFF_GRU1O   2457600u    // 128*200*64
#define OFF_GRU2O   4096000u
#define OFF_XP1     5734400u    // 128*100*192
#define OFF_XP2     8192000u
#define OFF_ZP1     10649600u   // 100*192
#define OFF_ZP2     10668800u
#define OFF_ZINC1   10688000u   // 100*64
#define OFF_ZINC2   10694400u
#define OFF_ZITC1   10700800u   // 200*64
#define OFF_ZITC2   10713600u
#define OFF_G3      10726400u   // 3*128
#define OFF_W4      10726784u   // 4*128
#define OFF_C4      10727296u   // 4
#define OFF_U1      10727300u   // 128*64
#define OFF_U2      10735492u

__device__ __forceinline__ float sigf(float x) { return 1.0f / (1.0f + __expf(-x)); }
__device__ __forceinline__ float tanhf_(float x) { return 1.0f - 2.0f / (__expf(2.0f * x) + 1.0f); }
__device__ __forceinline__ float rl(float v, int l) {
  return __int_as_float(__builtin_amdgcn_readlane(__float_as_int(v), l));
}

// ---------------- 1) gathers: s1raw, s2raw, i_all ----------------
__global__ void k_gather(const int* __restrict__ i_node, const int* __restrict__ neg,
                         const int* __restrict__ seq1, const int* __restrict__ seq2,
                         const float* __restrict__ emb, float* __restrict__ ws) {
  int tid = threadIdx.x;
  int r = blockIdx.x * 4 + (tid >> 6);
  int d = tid & 63;
  long idx;
  float* dst;
  if (r < 12800) {
    idx = seq1[r];
    dst = ws + OFF_S1RAW + (size_t)r * 64;
  } else if (r < 25600) {
    int rr = r - 12800;
    idx = seq2[rr];
    dst = ws + OFF_S2RAW + (size_t)rr * 64;
  } else {
    int rr = r - 25600;
    int b = rr / 100, i = rr % 100;
    idx = (i == 0) ? i_node[b] : neg[b * 99 + i - 1];
    dst = ws + OFF_IALL + (size_t)rr * 64;
  }
  dst[d] = emb[idx * 64 + d];
}

// ---------------- 2) per-batch max pairwise dot ----------------
// g[b] = max_{l,m} dot(A[b,l,:], B[b,m,:]).  Chunked by 100 rows, k-major LDS.
__global__ __launch_bounds__(256) void k_gmax(const float* __restrict__ A0, const float* __restrict__ B0, float* g0,
                                              const float* __restrict__ A1, const float* __restrict__ B1, float* g1,
                                              int L, int nbhalf) {
  int half = blockIdx.x / nbhalf;
  int b = blockIdx.x % nbhalf;
  const float* A = half ? A1 : A0;
  const float* B = half ? B1 : B0;
  float* gout = half ? g1 : g0;
  __shared__ __align__(16) float SA[64 * 104];
  __shared__ __align__(16) float SB[64 * 104];
  __shared__ float red[4];
  int tid = threadIdx.x;
  int nch = L / 100;
  float gm = -1e30f;
  for (int ai = 0; ai < nch; ++ai) {
    for (int bi = 0; bi < nch; ++bi) {
      __syncthreads();
      for (int e = tid; e < 6400; e += 256) {
        int l = e >> 6, k = e & 63;
        SA[k * 104 + l] = A[((size_t)b * L + ai * 100 + l) * 64 + k];
        SB[k * 104 + l] = B[((size_t)b * L + bi * 100 + l) * 64 + k];
      }
      __syncthreads();
      for (int id = tid; id < 625; id += 256) {
        int ti = id / 25, tj = id % 25;
        int l0 = ti * 4, m0 = tj * 4;
        float acc[4][4];
#pragma unroll
        for (int x = 0; x < 4; ++x)
#pragma unroll
          for (int y = 0; y < 4; ++y) acc[x][y] = 0.0f;
#pragma unroll 16
        for (int k = 0; k < 64; ++k) {
          const float4 av = *reinterpret_cast<const float4*>(&SA[k * 104 + l0]);
          const float4 bv = *reinterpret_cast<const float4*>(&SB[k * 104 + m0]);
          float aa[4] = {av.x, av.y, av.z, av.w};
          float bb[4] = {bv.x, bv.y, bv.z, bv.w};
#pragma unroll
          for (int x = 0; x < 4; ++x)
#pragma unroll
            for (int y = 0; y < 4; ++y) acc[x][y] = fmaf(aa[x], bb[y], acc[x][y]);
        }
        float tm = acc[0][0];
#pragma unroll
        for (int x = 0; x < 4; ++x)
#pragma unroll
          for (int y = 0; y < 4; ++y) tm = fmaxf(tm, acc[x][y]);
        gm = fmaxf(gm, tm);
      }
    }
  }
  for (int off = 32; off; off >>= 1) gm = fmaxf(gm, __shfl_xor(gm, off, 64));
  if ((tid & 63) == 0) red[tid >> 6] = gm;
  __syncthreads();
  if (tid == 0) gout[b] = fmaxf(fmaxf(red[0], red[1]), fmaxf(red[2], red[3]));
}

// ---------------- 3) softmax mask -> w[j]=Wbs[j]*mask[j], c=sum(Wbs) ----------------
__global__ void k_mask(const float* g0, const float* Wbs0, float* w0, float* c0,
                       const float* g1, const float* Wbs1, float* w1, float* c1) {
  int blk = blockIdx.x, tid = threadIdx.x;
  const float* g = blk ? g1 : g0;
  const float* Wbs = blk ? Wbs1 : Wbs0;
  float* w = blk ? w1 : w0;
  float* c = blk ? c1 : c0;
  __shared__ float ra[2], rb[2], rc[2];
  float gv = g[tid];
  float mx = gv;
  for (int off = 32; off; off >>= 1) mx = fmaxf(mx, __shfl_xor(mx, off, 64));
  if ((tid & 63) == 0) ra[tid >> 6] = mx;
  __syncthreads();
  mx = fmaxf(ra[0], ra[1]);
  float e = __expf(gv - mx);
  float sm = e;
  for (int off = 32; off; off >>= 1) sm += __shfl_xor(sm, off, 64);
  if ((tid & 63) == 0) rb[tid >> 6] = sm;
  __syncthreads();
  float soft = e / (rb[0] + rb[1]);
  float wb = Wbs[tid];
  w[tid] = (soft > TH) ? wb : 0.0f;
  float cs = wb;
  for (int off = 32; off; off >>= 1) cs += __shfl_xor(cs, off, 64);
  if ((tid & 63) == 0) rc[tid >> 6] = cs;
  __syncthreads();
  if (tid == 0) c[0] = rc[0] + rc[1];
}

// ---------------- 4) z[l,:] = (sum_j w[j]*other[j,l,:]) @ Wnn^T + c*bnn + bbs ----------------
__global__ void k_z(const float* o0, const float* w0, const float* Wnn0, const float* bnn0, const float* c0, const float* bbs0, float* z0,
                    const float* o1, const float* w1, const float* Wnn1, const float* bnn1, const float* c1, const float* bbs1, float* z1,
                    int L) {
  int comp = blockIdx.x / L;
  int l = blockIdx.x % L;
  const float* other = comp ? o1 : o0;
  const float* wv = comp ? w1 : w0;
  const float* Wnn = comp ? Wnn1 : Wnn0;
  const float* bnn = comp ? bnn1 : bnn0;
  const float* cp = comp ? c1 : c0;
  const float* bbs = comp ? bbs1 : bbs0;
  float* zout = comp ? z1 : z0;
  int d = threadIdx.x;
  float td = 0.0f;
#pragma unroll 4
  for (int j = 0; j < 128; ++j) td = fmaf(wv[j], other[((size_t)j * L + l) * 64 + d], td);
  __shared__ float tl[64];
  tl[d] = td;
  __syncthreads();
  float acc = fmaf(cp[0], bnn[d], bbs[0]);
#pragma unroll 8
  for (int k = 0; k < 64; ++k) acc = fmaf(tl[k], Wnn[d * 64 + k], acc);
  zout[l * 64 + d] = acc;
}

// ---------------- 5) input projections: out = X @ Wih^T + bih (rows x 192) ----------------
__global__ __launch_bounds__(192) void k_xproj(const float* __restrict__ s1raw, const float* __restrict__ s2raw,
                                               const float* __restrict__ zi1, const float* __restrict__ zi2,
                                               const float* __restrict__ W1, const float* __restrict__ b1,
                                               const float* __restrict__ W2, const float* __restrict__ b2,
                                               float* xp1, float* xp2, float* zp1, float* zp2) {
  int blk = blockIdx.x;
  const float* X;
  const float* W;
  const float* bi;
  float* out;
  int nrows, lb;
  if (blk < 800)        { X = s1raw; W = W1; bi = b1; out = xp1; nrows = 12800; lb = blk; }
  else if (blk < 1600)  { X = s2raw; W = W2; bi = b2; out = xp2; nrows = 12800; lb = blk - 800; }
  else if (blk < 1607)  { X = zi1;   W = W1; bi = b1; out = zp1; nrows = 100;   lb = blk - 1600; }
  else                  { X = zi2;   W = W2; bi = b2; out = zp2; nrows = 100;   lb = blk - 1607; }
  int row0 = lb * 16;
  int j = threadIdx.x;  // 0..191
  __shared__ float xt[16 * 64];
  int rmax = nrows - row0;
  if (rmax > 16) rmax = 16;
  int lim = rmax * 64;
  for (int e = j; e < lim; e += 192) xt[e] = X[(size_t)row0 * 64 + e];
  __syncthreads();
  float wreg[64];
#pragma unroll
  for (int k = 0; k < 64; ++k) wreg[k] = W[j * 64 + k];
  float bj = bi[j];
  for (int r = 0; r < rmax; ++r) {
    float acc = bj;
#pragma unroll
    for (int k = 0; k < 64; ++k) acc = fmaf(xt[r * 64 + k], wreg[k], acc);
    out[(size_t)(row0 + r) * 192 + j] = acc;
  }
}

// ---------------- 6) GRU scan: one wave per (domain, sample) ----------------
__global__ __launch_bounds__(64, 1) void k_scan(const float* __restrict__ xp1, const float* __restrict__ xp2,
                                                const float* __restrict__ zp1, const float* __restrict__ zp2,
                                                const float* __restrict__ Whh1, const float* __restrict__ bhh1,
                                                const float* __restrict__ Whh2, const float* __restrict__ bhh2,
                                                float* o1, float* o2) {
  int dom = blockIdx.x >> 7;
  int bb = blockIdx.x & 127;
  const float* xp = dom ? xp2 : xp1;
  const float* zp = dom ? zp2 : zp1;
  const float* Whh = dom ? Whh2 : Whh1;
  const float* bhh = dom ? bhh2 : bhh1;
  float* out = (dom ? o2 : o1) + (size_t)bb * 200 * 64;
  int i = threadIdx.x;  // lane owns h[i]
  float wr[64], wz[64], wn[64];
#pragma unroll
  for (int k = 0; k < 64; ++k) {
    wr[k] = Whh[i * 64 + k];
    wz[k] = Whh[(64 + i) * 64 + k];
    wn[k] = Whh[(128 + i) * 64 + k];
  }
  float br = bhh[i], bz = bhh[64 + i], bn = bhh[128 + i];
  float h = 0.0f;
  const float* p0 = xp + (size_t)bb * 100 * 192;
  float xr = p0[i], xz = p0[64 + i], xn = p0[128 + i];
  for (int t = 0; t < 200; ++t) {
    float nxr = 0.f, nxz = 0.f, nxn = 0.f;
    if (t < 199) {
      const float* pn = (t + 1 < 100) ? xp + ((size_t)bb * 100 + (t + 1)) * 192
                                      : zp + (size_t)(t + 1 - 100) * 192;
      nxr = pn[i];
      nxz = pn[64 + i];
      nxn = pn[128 + i];
    }
    float ar = br, az = bz, an = bn;
#pragma unroll
    for (int k = 0; k < 64; ++k) {
      float hk = rl(h, k);
      ar = fmaf(hk, wr[k], ar);
      az = fmaf(hk, wz[k], az);
      an = fmaf(hk, wn[k], an);
    }
    float r = sigf(xr + ar);
    float z = sigf(xz + az);
    float n = tanhf_(xn + r * an);
    h = n + z * (h - n);
    out[t * 64 + i] = h;
    xr = nxr; xz = nxz; xn = nxn;
  }
}

// ---------------- 7) u = (sum_t gru + sum_l z)/400 ----------------
__global__ void k_mean(const float* g1o, const float* g2o,
                       const float* zi1, const float* zi2,
                       float* u1, float* u2) {
  int dom = blockIdx.x >> 7, bb = blockIdx.x & 127, d = threadIdx.x;
  const float* s = dom ? g2o : g1o;
  const float* z = dom ? zi2 : zi1;
  float* u = dom ? u2 : u1;
  float acc = 0.0f;
  const float* sp = s + (size_t)bb * 200 * 64 + d;
#pragma unroll 4
  for (int t = 0; t < 200; ++t) acc += sp[t * 64];
#pragma unroll 4
  for (int l = 0; l < 200; ++l) acc += z[l * 64 + d];
  u[bb * 64 + d] = acc * 0.0025f;
}

// ---------------- 8) predictor MLP ----------------
__global__ __launch_bounds__(512, 2) void k_pred(const float* __restrict__ u1, const float* __restrict__ u2,
                                                 const float* __restrict__ iall,
                                                 const float* __restrict__ W1, const float* __restrict__ b1v,
                                                 const float* __restrict__ w2v, const float* __restrict__ b2v,
                                                 float* __restrict__ outp) {
  int p = blockIdx.x >> 7, bb = blockIdx.x & 127;
  const float* u = p ? u2 : u1;
  int tid = threadIdx.x;
  int j = tid & 127, g = tid >> 7, lane = tid & 63;
  float wrow[128];
#pragma unroll
  for (int k = 0; k < 128; ++k) wrow[k] = W1[j * 128 + k];
  float b1j = b1v[j], w2j = w2v[j], b2 = b2v[0];
  float ucopy = u[bb * 64 + lane];
  __shared__ float red[8];
  float* ob = outp + (size_t)p * 12800 + bb * 100;
  for (int m = 0; m < 25; ++m) {
    int i = g + 4 * m;
    float vcopy = iall[((size_t)bb * 100 + i) * 64 + lane];
    float acc = b1j;
#pragma unroll
    for (int k = 0; k < 64; ++k) acc = fmaf(rl(ucopy, k), wrow[k], acc);
#pragma unroll
    for (int k = 0; k < 64; ++k) acc = fmaf(rl(vcopy, k), wrow[64 + k], acc);
    float hg = fmaxf(acc, 0.0f);
    float part = w2j * hg;
    for (int off = 32; off; off >>= 1) part += __shfl_xor(part, off, 64);
    if (lane == 0) red[tid >> 6] = part;
    __syncthreads();
    if ((tid & 127) == 0) {
      float sres = red[tid >> 6] + red[(tid >> 6) + 1] + b2;
      ob[i] = 1.0f / (1.0f + __expf(-sres));
    }
    __syncthreads();
  }
}

// ---------------- launcher ----------------
extern "C" void kernel_launch(void* const* d_in, const int* in_sizes, int n_in,
                              void* d_out, int out_size, void* d_ws, size_t ws_size,
                              hipStream_t stream) {
  const int* i_node = (const int*)d_in[1];
  const int* neg = (const int*)d_in[2];
  const int* seq1 = (const int*)d_in[3];
  const int* seq2 = (const int*)d_in[4];
  const float* emb = (const float*)d_in[7];
  const float* inc1_Wnn = (const float*)d_in[8];
  const float* inc1_bnn = (const float*)d_in[9];
  const float* inc1_Wbs = (const float*)d_in[10];
  const float* inc1_bbs = (const float*)d_in[11];
  const float* inc2_Wnn = (const float*)d_in[12];
  const float* inc2_bnn = (const float*)d_in[13];
  const float* inc2_Wbs = (const float*)d_in[14];
  const float* inc2_bbs = (const float*)d_in[15];
  const float* itc1_Wnn = (const float*)d_in[16];
  const float* itc1_bnn = (const float*)d_in[17];
  const float* itc1_Wbs = (const float*)d_in[18];
  const float* itc1_bbs = (const float*)d_in[19];
  const float* itc2_Wnn = (const float*)d_in[20];
  const float* itc2_bnn = (const float*)d_in[21];
  const float* itc2_Wbs = (const float*)d_in[22];
  const float* itc2_bbs = (const float*)d_in[23];
  const float* gru1_Wih = (const float*)d_in[24];
  const float* gru1_Whh = (const float*)d_in[25];
  const float* gru1_bih = (const float*)d_in[26];
  const float* gru1_bhh = (const float*)d_in[27];
  const float* gru2_Wih = (const float*)d_in[28];
  const float* gru2_Whh = (const float*)d_in[29];
  const float* gru2_bih = (const float*)d_in[30];
  const float* gru2_bhh = (const float*)d_in[31];
  const float* fc1_W = (const float*)d_in[32];
  const float* fc1_b = (const float*)d_in[33];
  const float* fc2_W = (const float*)d_in[34];
  const float* fc2_b = (const float*)d_in[35];

  float* ws = (float*)d_ws;
  float* out = (float*)d_out;
  float* s1raw = ws + OFF_S1RAW;
  float* s2raw = ws + OFF_S2RAW;
  float* iall = ws + OFF_IALL;
  float* gru1o = ws + OFF_GRU1O;
  float* gru2o = ws + OFF_GRU2O;
  float* xp1 = ws + OFF_XP1;
  float* xp2 = ws + OFF_XP2;
  float* zp1 = ws + OFF_ZP1;
  float* zp2 = ws + OFF_ZP2;
  float* zinc1 = ws + OFF_ZINC1;
  float* zinc2 = ws + OFF_ZINC2;
  float* zitc1 = ws + OFF_ZITC1;
  float* zitc2 = ws + OFF_ZITC2;
  float* g3 = ws + OFF_G3;
  float* w4 = ws + OFF_W4;
  float* c4 = ws + OFF_C4;
  float* u1 = ws + OFF_U1;
  float* u2 = ws + OFF_U2;

  // 1) gathers
  k_gather<<<9600, 256, 0, stream>>>(i_node, neg, seq1, seq2, emb, ws);
  // 2) inner-comp g (self-Gram max) for both domains
  k_gmax<<<256, 256, 0, stream>>>(s1raw, s1raw, g3, s2raw, s2raw, g3 + 128, 100, 128);
  // 3) masks + folded Wbs for inc1/inc2
  k_mask<<<2, 128, 0, stream>>>(g3, inc1_Wbs, w4, c4, g3 + 128, inc2_Wbs, w4 + 128, c4 + 1);
  // 4) z for inner comps
  k_z<<<200, 64, 0, stream>>>(s1raw, w4, inc1_Wnn, inc1_bnn, c4, inc1_bbs, zinc1,
                              s2raw, w4 + 128, inc2_Wnn, inc2_bnn, c4 + 1, inc2_bbs, zinc2, 100);
  // 5) GRU input projections (per-b rows t<100, shared rows t>=100)
  k_xproj<<<1614, 192, 0, stream>>>(s1raw, s2raw, zinc1, zinc2,
                                    gru1_Wih, gru1_bih, gru2_Wih, gru2_bih,
                                    xp1, xp2, zp1, zp2);
  // 6) GRU scans (both domains concurrently)
  k_scan<<<256, 64, 0, stream>>>(xp1, xp2, zp1, zp2, gru1_Whh, gru1_bhh, gru2_Whh, gru2_bhh,
                                 gru1o, gru2o);
  // 7) inter-comp g (shared by itc1/itc2)
  k_gmax<<<128, 256, 0, stream>>>(gru1o, gru2o, g3 + 256, gru1o, gru2o, g3 + 256, 200, 128);
  // 8) masks for itc1/itc2 (same g, different Wbs)
  k_mask<<<2, 128, 0, stream>>>(g3 + 256, itc1_Wbs, w4 + 256, c4 + 2,
                                g3 + 256, itc2_Wbs, w4 + 384, c4 + 3);
  // 9) z for inter comps (itc1 uses gru2 output, itc2 uses gru1 output)
  k_z<<<400, 64, 0, stream>>>(gru2o, w4 + 256, itc1_Wnn, itc1_bnn, c4 + 2, itc1_bbs, zitc1,
                              gru1o, w4 + 384, itc2_Wnn, itc2_bnn, c4 + 3, itc2_bbs, zitc2, 200);
  // 10) user means
  k_mean<<<256, 64, 0, stream>>>(gru1o, gru2o, zitc1, zitc2, u1, u2);
  // 11) predictor
  k_pred<<<256, 512, 0, stream>>>(u1, u2, iall, fc1_W, fc1_b, fc2_W, fc2_b, out);
}

// Round 2
// 698.027 us; speedup vs baseline: 1.0397x; 1.0397x over previous
//
#include <hip/hip_runtime.h>
#include <hip/hip_bf16.h>
#include <cstdint>
#include <cstddef>

// ---------------- model constants ----------------
#define TH 0.007f

// ---------------- workspace layout (float offsets) ----------------
#define OFF_S1RAW   0u          // 128*100*64
#define OFF_S2RAW   819200u
#define OFF_IALL    1638400u    // 128*100*64
#define OFF_GRU1O   2457600u    // 128*200*64
#define OFF_GRU2O   4096000u
#define OFF_XP1     5734400u    // 128*100*192
#define OFF_XP2     8192000u
#define OFF_ZP1     10649600u   // 100*192
#define OFF_ZP2     10668800u
#define OFF_ZINC1   10688000u   // 100*64
#define OFF_ZINC2   10694400u
#define OFF_ZITC1   10700800u   // 200*64
#define OFF_ZITC2   10713600u
#define OFF_G3      10726400u   // 3*128
#define OFF_U1      10727300u   // 128*64
#define OFF_U2      10735492u

__device__ __forceinline__ float sigf(float x) { return 1.0f / (1.0f + __expf(-x)); }
__device__ __forceinline__ float tanhf_(float x) { return 1.0f - 2.0f / (__expf(2.0f * x) + 1.0f); }

// ---------------- 1) gathers: s1raw, s2raw, i_all ----------------
__global__ void k_gather(const int* __restrict__ i_node, const int* __restrict__ neg,
                         const int* __restrict__ seq1, const int* __restrict__ seq2,
                         const float* __restrict__ emb, float* __restrict__ ws) {
  int tid = threadIdx.x;
  int r = blockIdx.x * 4 + (tid >> 6);
  int d = tid & 63;
  long idx;
  float* dst;
  if (r < 12800) {
    idx = seq1[r];
    dst = ws + OFF_S1RAW + (size_t)r * 64;
  } else if (r < 25600) {
    int rr = r - 12800;
    idx = seq2[rr];
    dst = ws + OFF_S2RAW + (size_t)rr * 64;
  } else {
    int rr = r - 25600;
    int b = rr / 100, i = rr % 100;
    idx = (i == 0) ? i_node[b] : neg[b * 99 + i - 1];
    dst = ws + OFF_IALL + (size_t)rr * 64;
  }
  dst[d] = emb[idx * 64 + d];
}

// ---------------- 2) per-batch max pairwise dot ----------------
__global__ __launch_bounds__(256) void k_gmax(const float* __restrict__ A0, const float* __restrict__ B0, float* g0,
                                              const float* __restrict__ A1, const float* __restrict__ B1, float* g1,
                                              int L, int nbhalf) {
  int half = blockIdx.x / nbhalf;
  int b = blockIdx.x % nbhalf;
  const float* A = half ? A1 : A0;
  const float* B = half ? B1 : B0;
  float* gout = half ? g1 : g0;
  __shared__ __align__(16) float SA[64 * 104];
  __shared__ __align__(16) float SB[64 * 104];
  __shared__ float red[4];
  int tid = threadIdx.x;
  int nch = L / 100;
  float gm = -1e30f;
  for (int ai = 0; ai < nch; ++ai) {
    for (int bi = 0; bi < nch; ++bi) {
      __syncthreads();
      for (int e = tid; e < 6400; e += 256) {
        int l = e >> 6, k = e & 63;
        SA[k * 104 + l] = A[((size_t)b * L + ai * 100 + l) * 64 + k];
        SB[k * 104 + l] = B[((size_t)b * L + bi * 100 + l) * 64 + k];
      }
      __syncthreads();
      for (int id = tid; id < 625; id += 256) {
        int ti = id / 25, tj = id % 25;
        int l0 = ti * 4, m0 = tj * 4;
        float acc[4][4];
#pragma unroll
        for (int x = 0; x < 4; ++x)
#pragma unroll
          for (int y = 0; y < 4; ++y) acc[x][y] = 0.0f;
#pragma unroll 16
        for (int k = 0; k < 64; ++k) {
          const float4 av = *reinterpret_cast<const float4*>(&SA[k * 104 + l0]);
          const float4 bv = *reinterpret_cast<const float4*>(&SB[k * 104 + m0]);
          float aa[4] = {av.x, av.y, av.z, av.w};
          float bb[4] = {bv.x, bv.y, bv.z, bv.w};
#pragma unroll
          for (int x = 0; x < 4; ++x)
#pragma unroll
            for (int y = 0; y < 4; ++y) acc[x][y] = fmaf(aa[x], bb[y], acc[x][y]);
        }
        float tm = acc[0][0];
#pragma unroll
        for (int x = 0; x < 4; ++x)
#pragma unroll
          for (int y = 0; y < 4; ++y) tm = fmaxf(tm, acc[x][y]);
        gm = fmaxf(gm, tm);
      }
    }
  }
  for (int off = 32; off; off >>= 1) gm = fmaxf(gm, __shfl_xor(gm, off, 64));
  if ((tid & 63) == 0) red[tid >> 6] = gm;
  __syncthreads();
  if (tid == 0) gout[b] = fmaxf(fmaxf(red[0], red[1]), fmaxf(red[2], red[3]));
}

// ---------------- 3) z (with fused softmax mask): one wave per (comp,l) ----------------
__global__ void k_z(const float* o0, const float* g0, const float* Wbs0, const float* Wnn0, const float* bnn0, const float* bbs0, float* z0,
                    const float* o1, const float* g1, const float* Wbs1, const float* Wnn1, const float* bnn1, const float* bbs1, float* z1,
                    int L) {
  int comp = blockIdx.x / L;
  int l = blockIdx.x % L;
  const float* other = comp ? o1 : o0;
  const float* g = comp ? g1 : g0;
  const float* Wbs = comp ? Wbs1 : Wbs0;
  const float* Wnn = comp ? Wnn1 : Wnn0;
  const float* bnn = comp ? bnn1 : bnn0;
  const float* bbs = comp ? bbs1 : bbs0;
  float* zout = comp ? z1 : z0;
  int d = threadIdx.x;  // one wave
  __shared__ float w_s[128];
  __shared__ float tl[64];
  // fused softmax(g)>TH mask -> w_s[j] = Wbs[j]*mask[j]; cs = sum(Wbs)
  float ga = g[d], gb = g[d + 64];
  float mx = fmaxf(ga, gb);
  for (int off = 32; off; off >>= 1) mx = fmaxf(mx, __shfl_xor(mx, off, 64));
  float ea = __expf(ga - mx), eb = __expf(gb - mx);
  float sm = ea + eb;
  for (int off = 32; off; off >>= 1) sm += __shfl_xor(sm, off, 64);
  float wa = Wbs[d], wb = Wbs[d + 64];
  w_s[d] = (ea / sm > TH) ? wa : 0.0f;
  w_s[d + 64] = (eb / sm > TH) ? wb : 0.0f;
  float cs = wa + wb;
  for (int off = 32; off; off >>= 1) cs += __shfl_xor(cs, off, 64);
  __syncthreads();
  float td = 0.0f;
#pragma unroll 4
  for (int j = 0; j < 128; ++j) td = fmaf(w_s[j], other[((size_t)j * L + l) * 64 + d], td);
  tl[d] = td;
  __syncthreads();
  float acc = fmaf(cs, bnn[d], bbs[0]);
#pragma unroll 8
  for (int k = 0; k < 64; ++k) acc = fmaf(tl[k], Wnn[d * 64 + k], acc);
  zout[l * 64 + d] = acc;
}

// ---------------- 4) input projections: out = X @ Wih^T + bih ----------------
__global__ __launch_bounds__(192) void k_xproj(const float* __restrict__ s1raw, const float* __restrict__ s2raw,
                                               const float* __restrict__ zi1, const float* __restrict__ zi2,
                                               const float* __restrict__ W1, const float* __restrict__ b1,
                                               const float* __restrict__ W2, const float* __restrict__ b2,
                                               float* xp1, float* xp2, float* zp1, float* zp2) {
  int blk = blockIdx.x;
  const float* X;
  const float* W;
  const float* bi;
  float* out;
  int nrows, lb;
  if (blk < 800)        { X = s1raw; W = W1; bi = b1; out = xp1; nrows = 12800; lb = blk; }
  else if (blk < 1600)  { X = s2raw; W = W2; bi = b2; out = xp2; nrows = 12800; lb = blk - 800; }
  else if (blk < 1607)  { X = zi1;   W = W1; bi = b1; out = zp1; nrows = 100;   lb = blk - 1600; }
  else                  { X = zi2;   W = W2; bi = b2; out = zp2; nrows = 100;   lb = blk - 1607; }
  int row0 = lb * 16;
  int j = threadIdx.x;  // 0..191
  __shared__ float xt[16 * 64];
  int rmax = nrows - row0;
  if (rmax > 16) rmax = 16;
  int lim = rmax * 64;
  for (int e = j; e < lim; e += 192) xt[e] = X[(size_t)row0 * 64 + e];
  __syncthreads();
  float wreg[64];
#pragma unroll
  for (int k = 0; k < 64; ++k) wreg[k] = W[j * 64 + k];
  float bj = bi[j];
  for (int r = 0; r < rmax; ++r) {
    float acc = bj;
#pragma unroll
    for (int k = 0; k < 64; ++k) acc = fmaf(xt[r * 64 + k], wreg[k], acc);
    out[(size_t)(row0 + r) * 192 + j] = acc;
  }
}

// ---------------- 5) GRU scan: 3 waves (gates r,z,n) per (domain, sample) ----------------
__global__ __launch_bounds__(192) void k_scan(const float* __restrict__ xp1, const float* __restrict__ xp2,
                                              const float* __restrict__ zp1, const float* __restrict__ zp2,
                                              const float* __restrict__ Whh1, const float* __restrict__ bhh1,
                                              const float* __restrict__ Whh2, const float* __restrict__ bhh2,
                                              float* o1, float* o2) {
  int dom = blockIdx.x >> 7;
  int bb = blockIdx.x & 127;
  const float* xp = dom ? xp2 : xp1;
  const float* zp = dom ? zp2 : zp1;
  const float* Whh = dom ? Whh2 : Whh1;
  const float* bhh = dom ? bhh2 : bhh1;
  float* out = (dom ? o2 : o1) + (size_t)bb * 200 * 64;
  int tid = threadIdx.x;
  int g = tid >> 6;   // wave = gate: 0=r, 1=z, 2=n
  int i = tid & 63;   // output index within gate
  __shared__ __align__(16) float h_s[64];
  __shared__ float r_s[64];
  __shared__ float z_s[64];
  // 64 weight registers per lane: row (g*64+i) of Whh
  float w[64];
  const float* wrow = Whh + (size_t)(g * 64 + i) * 64;
#pragma unroll
  for (int k4 = 0; k4 < 16; ++k4) {
    float4 wv = *reinterpret_cast<const float4*>(wrow + 4 * k4);
    w[4 * k4 + 0] = wv.x; w[4 * k4 + 1] = wv.y; w[4 * k4 + 2] = wv.z; w[4 * k4 + 3] = wv.w;
  }
  float bg = bhh[g * 64 + i];
  if (tid < 64) h_s[tid] = 0.0f;
  float h_i = 0.0f;                 // wave 2, lane i keeps h[i]
  float x_cur = xp[((size_t)bb * 100) * 192 + g * 64 + i];
  __syncthreads();
  for (int t = 0; t < 200; ++t) {
    // prefetch next x (global; t>=100 rows are the shared z-projection)
    float x_nxt = 0.0f;
    if (t < 199) {
      const float* pn = (t < 99) ? xp + ((size_t)bb * 100 + t + 1) * 192
                                 : zp + (size_t)(t + 1 - 100) * 192;
      x_nxt = pn[g * 64 + i];
    }
    // a = bg + sum_k h[k]*w[k]  (h broadcast from LDS, 4 partial chains)
    float a0 = bg, a1 = 0.0f, a2 = 0.0f, a3 = 0.0f;
#pragma unroll
    for (int k4 = 0; k4 < 16; ++k4) {
      float4 hv = *reinterpret_cast<const float4*>(&h_s[4 * k4]);
      a0 = fmaf(hv.x, w[4 * k4 + 0], a0);
      a1 = fmaf(hv.y, w[4 * k4 + 1], a1);
      a2 = fmaf(hv.z, w[4 * k4 + 2], a2);
      a3 = fmaf(hv.w, w[4 * k4 + 3], a3);
    }
    float a = (a0 + a1) + (a2 + a3);
    if (g == 0)      r_s[i] = sigf(x_cur + a);
    else if (g == 1) z_s[i] = sigf(x_cur + a);
    __syncthreads();  // A: r_s/z_s published; everyone done reading h_s
    if (g == 2) {
      float r = r_s[i], z = z_s[i];
      float n = tanhf_(x_cur + r * a);
      h_i = n + z * (h_i - n);
      h_s[i] = h_i;
      out[t * 64 + i] = h_i;
    }
    __syncthreads();  // B: new h_s visible for next step
    x_cur = x_nxt;
  }
}

// ---------------- 6) u = (sum_t gru + sum_l z)/400 ----------------
__global__ void k_mean(const float* g1o, const float* g2o,
                       const float* zi1, const float* zi2,
                       float* u1, float* u2) {
  int dom = blockIdx.x >> 7, bb = blockIdx.x & 127, d = threadIdx.x;
  const float* s = dom ? g2o : g1o;
  const float* z = dom ? zi2 : zi1;
  float* u = dom ? u2 : u1;
  float acc = 0.0f;
  const float* sp = s + (size_t)bb * 200 * 64 + d;
#pragma unroll 4
  for (int t = 0; t < 200; ++t) acc += sp[t * 64];
#pragma unroll 4
  for (int l = 0; l < 200; ++l) acc += z[l * 64 + d];
  u[bb * 64 + d] = acc * 0.0025f;
}

// ---------------- 7) predictor MLP: lane = item, W1 rows via scalar loads ----------------
__global__ __launch_bounds__(256) void k_pred(const float* __restrict__ u1, const float* __restrict__ u2,
                                              const float* __restrict__ iall,
                                              const float* __restrict__ W1, const float* __restrict__ b1v,
                                              const float* __restrict__ w2v, const float* __restrict__ b2v,
                                              float* __restrict__ outp) {
  int p = blockIdx.x >> 7, bb = blockIdx.x & 127;
  const float* u = (p ? u2 : u1) + bb * 64;
  int tid = threadIdx.x;
  int lane = tid & 63;
  int jh = (tid >> 6) & 1;  // which half of the 128 hidden neurons
  int ih = tid >> 7;        // which half of the 100 items
  int i = ih * 64 + lane;
  bool act = i < 100;
  __shared__ float aU[128];
  __shared__ float part[2][100];
  // prologue: aU[j] = b1[j] + u . W1[j, :64]   (j = tid for tid<128)
  if (tid < 128) {
    int j = tid;
    float acc = b1v[j];
#pragma unroll 8
    for (int k = 0; k < 64; ++k) acc = fmaf(u[k], W1[j * 128 + k], acc);
    aU[j] = acc;
  }
  // V row for this item, in registers
  float V[64];
  const float* vp = iall + ((size_t)bb * 100 + (act ? i : 0)) * 64;
#pragma unroll
  for (int k4 = 0; k4 < 16; ++k4) {
    float4 vv = *reinterpret_cast<const float4*>(vp + 4 * k4);
    V[4 * k4 + 0] = vv.x; V[4 * k4 + 1] = vv.y; V[4 * k4 + 2] = vv.z; V[4 * k4 + 3] = vv.w;
  }
  __syncthreads();
  float acc_o = 0.0f;
  for (int j = jh * 64; j < jh * 64 + 64; ++j) {
    const float* wrow = W1 + j * 128 + 64;  // wave-uniform -> s_load
    float d0 = aU[j], d1 = 0.0f, d2 = 0.0f, d3 = 0.0f;
#pragma unroll
    for (int k = 0; k < 16; ++k) {
      d0 = fmaf(V[4 * k + 0], wrow[4 * k + 0], d0);
      d1 = fmaf(V[4 * k + 1], wrow[4 * k + 1], d1);
      d2 = fmaf(V[4 * k + 2], wrow[4 * k + 2], d2);
      d3 = fmaf(V[4 * k + 3], wrow[4 * k + 3], d3);
    }
    float hrelu = fmaxf((d0 + d1) + (d2 + d3), 0.0f);
    acc_o = fmaf(w2v[j], hrelu, acc_o);
  }
  if (act) part[jh][i] = acc_o;
  __syncthreads();
  if (act && jh == 0) {
    float s = part[0][i] + part[1][i] + b2v[0];
    outp[(size_t)p * 12800 + bb * 100 + i] = 1.0f / (1.0f + __expf(-s));
  }
}

// ---------------- launcher ----------------
extern "C" void kernel_launch(void* const* d_in, const int* in_sizes, int n_in,
                              void* d_out, int out_size, void* d_ws, size_t ws_size,
                              hipStream_t stream) {
  const int* i_node = (const int*)d_in[1];
  const int* neg = (const int*)d_in[2];
  const int* seq1 = (const int*)d_in[3];
  const int* seq2 = (const int*)d_in[4];
  const float* emb = (const float*)d_in[7];
  const float* inc1_Wnn = (const float*)d_in[8];
  const float* inc1_bnn = (const float*)d_in[9];
  const float* inc1_Wbs = (const float*)d_in[10];
  const float* inc1_bbs = (const float*)d_in[11];
  const float* inc2_Wnn = (const float*)d_in[12];
  const float* inc2_bnn = (const float*)d_in[13];
  const float* inc2_Wbs = (const float*)d_in[14];
  const float* inc2_bbs = (const float*)d_in[15];
  const float* itc1_Wnn = (const float*)d_in[16];
  const float* itc1_bnn = (const float*)d_in[17];
  const float* itc1_Wbs = (const float*)d_in[18];
  const float* itc1_bbs = (const float*)d_in[19];
  const float* itc2_Wnn = (const float*)d_in[20];
  const float* itc2_bnn = (const float*)d_in[21];
  const float* itc2_Wbs = (const float*)d_in[22];
  const float* itc2_bbs = (const float*)d_in[23];
  const float* gru1_Wih = (const float*)d_in[24];
  const float* gru1_Whh = (const float*)d_in[25];
  const float* gru1_bih = (const float*)d_in[26];
  const float* gru1_bhh = (const float*)d_in[27];
  const float* gru2_Wih = (const float*)d_in[28];
  const float* gru2_Whh = (const float*)d_in[29];
  const float* gru2_bih = (const float*)d_in[30];
  const float* gru2_bhh = (const float*)d_in[31];
  const float* fc1_W = (const float*)d_in[32];
  const float* fc1_b = (const float*)d_in[33];
  const float* fc2_W = (const float*)d_in[34];
  const float* fc2_b = (const float*)d_in[35];

  float* ws = (float*)d_ws;
  float* out = (float*)d_out;
  float* s1raw = ws + OFF_S1RAW;
  float* s2raw = ws + OFF_S2RAW;
  float* iall = ws + OFF_IALL;
  float* gru1o = ws + OFF_GRU1O;
  float* gru2o = ws + OFF_GRU2O;
  float* xp1 = ws + OFF_XP1;
  float* xp2 = ws + OFF_XP2;
  float* zp1 = ws + OFF_ZP1;
  float* zp2 = ws + OFF_ZP2;
  float* zinc1 = ws + OFF_ZINC1;
  float* zinc2 = ws + OFF_ZINC2;
  float* zitc1 = ws + OFF_ZITC1;
  float* zitc2 = ws + OFF_ZITC2;
  float* g3 = ws + OFF_G3;
  float* u1 = ws + OFF_U1;
  float* u2 = ws + OFF_U2;

  // 1) gathers
  k_gather<<<9600, 256, 0, stream>>>(i_node, neg, seq1, seq2, emb, ws);
  // 2) inner-comp g (self-Gram max) for both domains
  k_gmax<<<256, 256, 0, stream>>>(s1raw, s1raw, g3, s2raw, s2raw, g3 + 128, 100, 128);
  // 3) z for inner comps (mask fused)
  k_z<<<200, 64, 0, stream>>>(s1raw, g3, inc1_Wbs, inc1_Wnn, inc1_bnn, inc1_bbs, zinc1,
                              s2raw, g3 + 128, inc2_Wbs, inc2_Wnn, inc2_bnn, inc2_bbs, zinc2, 100);
  // 4) GRU input projections
  k_xproj<<<1614, 192, 0, stream>>>(s1raw, s2raw, zinc1, zinc2,
                                    gru1_Wih, gru1_bih, gru2_Wih, gru2_bih,
                                    xp1, xp2, zp1, zp2);
  // 5) GRU scans (3 waves per sample: gate-split, LDS h-broadcast)
  k_scan<<<256, 192, 0, stream>>>(xp1, xp2, zp1, zp2, gru1_Whh, gru1_bhh, gru2_Whh, gru2_bhh,
                                  gru1o, gru2o);
  // 6) inter-comp g (shared by itc1/itc2)
  k_gmax<<<128, 256, 0, stream>>>(gru1o, gru2o, g3 + 256, gru1o, gru2o, g3 + 256, 200, 128);
  // 7) z for inter comps (mask fused; itc1 uses gru2 output, itc2 uses gru1 output)
  k_z<<<400, 64, 0, stream>>>(gru2o, g3 + 256, itc1_Wbs, itc1_Wnn, itc1_bnn, itc1_bbs, zitc1,
                              gru1o, g3 + 256, itc2_Wbs, itc2_Wnn, itc2_bnn, itc2_bbs, zitc2, 200);
  // 8) user means
  k_mean<<<256, 64, 0, stream>>>(gru1o, gru2o, zitc1, zitc2, u1, u2);
  // 9) predictor
  k_pred<<<256, 256, 0, stream>>>(u1, u2, iall, fc1_W, fc1_b, fc2_W, fc2_b, out);
}